// Round 4
// baseline (210.500 us; speedup 1.0000x reference)
//
#include <hip/hip_runtime.h>

#define BB 16
#define TT 8192
#define NN 128                     // N_PRE == N_POST
constexpr int CHUNK = 128;         // time-steps per chunk (halved vs round 0)
constexpr int NCHB  = BB * TT / CHUNK;   // 1024 chunks
constexpr int NBLK  = NCHB / 2;          // 512 blocks, 2 chunks each -> 2 blocks/CU
constexpr int OUTN  = NN * NN;           // 16384
constexpr int GS    = 132;         // bufG row stride in halves (264 B, 8B-aligned)
constexpr int SLOTS = OUTN / 2;    // 8192 packed u32 slots per block-slice
constexpr int PROWS = 186;         // staged post rows per chunk: max m = 112+73 = 185
constexpr int NWAVE = 8;           // 512 threads
constexpr int WIN   = CHUNK / NWAVE;     // 16-step filter window per wave

typedef _Float16 f16x8 __attribute__((ext_vector_type(8)));
typedef _Float16 f16x2 __attribute__((ext_vector_type(2)));
typedef float    f32x4 __attribute__((ext_vector_type(4)));

__device__ __forceinline__ unsigned short h16(float x) {
    _Float16 h = (_Float16)x;
    return __builtin_bit_cast(unsigned short, h);
}
__device__ __forceinline__ unsigned int pack2(float x, float y) {
    return (unsigned int)h16(x) | ((unsigned int)h16(y) << 16);
}
__device__ __forceinline__ float2 ldL(const unsigned short* p_lds, int m, int q0) {
    const unsigned int v = *(const unsigned int*)&p_lds[m * NN + q0];
    const f16x2 h = __builtin_bit_cast(f16x2, v);
    return make_float2((float)h[0], (float)h[1]);
}

// grid 512 x 512 threads, 81,408 B LDS -> 2 blocks/CU resident, 16 waves/CU.
// ROUND-4: rounds 1-3 proved 1024-thr blocks are pinned at 64 VGPR (spill).
// Revert to 512 threads / 128 VGPR; get the TLP from a second RESIDENT BLOCK
// instead: CHUNK 256->128 shrinks LDS to 81,408 B (< 160KB/2), grid 256->512.
// Co-resident blocks share no barriers -> each fills the other's stalls.
// Pipeline per block (chunks c0=2bi, c1=2bi+1, same batch):
// stage c0 -> BAR -> filter c0 -> BAR -> [issue c1 loads | MFMA c0 | store c1]
// -> BAR -> filter c1 -> BAR -> [ps flush | MFMA c1] -> BAR -> wpost + partial.
template<bool ATOMIC>
__global__ __launch_bounds__(512, 4)
void stdp_main(const float* __restrict__ pre, const float* __restrict__ post,
               const int* __restrict__ dtp,
               unsigned int* __restrict__ part, float* __restrict__ wpost,
               float* __restrict__ outat)
{
    __shared__ __align__(16) unsigned short bufP[PROWS * NN];   // 47,616 B post tile
    __shared__ __align__(16) unsigned short bufG[NN * GS];      // 33,792 B g tile

    const int tid    = threadIdx.x;
    const int bi     = blockIdx.x;
    const int c0g    = bi * 2;           // global chunk ids c0g, c0g+1 (same batch)
    const int b      = c0g >> 6;         // 64 chunks of 128 per batch
    const int chunk0 = c0g & 63;         // even, 0..62
    const int t00    = chunk0 * CHUNK;
    const int t01    = t00 + CHUNK;
    const int wv     = tid >> 6;         // wave 0..7
    const int lane   = tid & 63;

    const float dtf = (float)(*dtp);
    const float r   = expf(-dtf * (1.0f / 20.0f));

    const float* pb = post + (size_t)b * TT * NN;
    const float* ab = pre  + (size_t)b * TT * NN;

    const int sc = tid & 31;             // staging: float4 column
    const int mr = tid >> 5;             // staging: starting row (0..15)

    // ---------- stage c0 post tile into bufP ----------
    // chunk0 <= 62 -> max t = 62*128 + 186 = 8122 < TT, no guard needed
    for (int m = mr; m < PROWS; m += 16) {
        const int t = t00 + 1 + m;
        const float4 v = *(const float4*)(pb + (size_t)t * NN + sc * 4);
        *(uint2*)&bufP[m * NN + sc * 4] = make_uint2(pack2(v.x, v.y), pack2(v.z, v.w));
    }
    __syncthreads();

    const int q0   = lane * 2;
    const int base = wv * WIN;           // window start (16 steps per wave)

    // ---------- filter: window WIN steps, 2 q per lane ----------
    unsigned int pk0[8], pk1[8];
    float ps0 = 0.f, ps1 = 0.f;          // accumulated across BOTH chunks
    // Startup g[15] = sum_{tau=1..59} r^tau * P[base+14+tau], 4 strided ILP
    // chains (dep depth 15). Then backward recurrence c=14..0:
    // g[c] = r*(g[c+1] + P[base+c]) - r^60 * P[base+c+59].
    #define FILTER_PHASE(SRC) {                                               \
        const float r2 = r * r, r3 = r2 * r, r4 = r2 * r2;                    \
        float2 p = ldL(SRC, base + 15, q0);      /* tau=1 */                  \
        ps0 += p.x; ps1 += p.y;                                               \
        float gx0 = r  * p.x, gy0 = r  * p.y;                                 \
        p = ldL(SRC, base + 16, q0);             /* tau=2 */                  \
        float gx1 = r2 * p.x, gy1 = r2 * p.y;                                 \
        p = ldL(SRC, base + 17, q0);             /* tau=3 */                  \
        float gx2 = r3 * p.x, gy2 = r3 * p.y;                                 \
        p = ldL(SRC, base + 18, q0);             /* tau=4 */                  \
        float gx3 = r4 * p.x, gy3 = r4 * p.y;                                 \
        float wA = r * r4, wB = r2 * r4, wC = r3 * r4, wD = r4 * r4;          \
        _Pragma("unroll")                                                     \
        for (int j = 1; j < 15; ++j) {                                        \
            p = ldL(SRC, base + 15 + 4 * j, q0);                              \
            gx0 = fmaf(wA, p.x, gx0); gy0 = fmaf(wA, p.y, gy0);               \
            p = ldL(SRC, base + 16 + 4 * j, q0);                              \
            gx1 = fmaf(wB, p.x, gx1); gy1 = fmaf(wB, p.y, gy1);               \
            p = ldL(SRC, base + 17 + 4 * j, q0);                              \
            gx2 = fmaf(wC, p.x, gx2); gy2 = fmaf(wC, p.y, gy2);               \
            if (j < 14) {                                                     \
                p = ldL(SRC, base + 18 + 4 * j, q0);                          \
                gx3 = fmaf(wD, p.x, gx3); gy3 = fmaf(wD, p.y, gy3);           \
            }                                                                 \
            wA *= r4; wB *= r4; wC *= r4; wD *= r4;                           \
        }                                                                     \
        const float r8 = r4 * r4, r16 = r8 * r8, r32 = r16 * r16;             \
        const float r60 = ((r32 * r16) * r8) * r4;                            \
        float gx = (gx0 + gx1) + (gx2 + gx3);                                 \
        float gy = (gy0 + gy1) + (gy2 + gy3);                                 \
        pk0[7] = (unsigned int)h16(gx) << 16;                                 \
        pk1[7] = (unsigned int)h16(gy) << 16;                                 \
        _Pragma("unroll")                                                     \
        for (int c = 14; c >= 0; --c) {                                       \
            const float2 p1  = ldL(SRC, base + c,      q0);                   \
            const float2 p60 = ldL(SRC, base + c + 59, q0);                   \
            gx = r * (gx + p1.x) - r60 * p60.x;                               \
            gy = r * (gy + p1.y) - r60 * p60.y;                               \
            ps0 += p1.x; ps1 += p1.y;                                         \
            if (c & 1) {                                                      \
                pk0[c >> 1] = (unsigned int)h16(gx) << 16;                    \
                pk1[c >> 1] = (unsigned int)h16(gy) << 16;                    \
            } else {                                                          \
                pk0[c >> 1] |= h16(gx);                                       \
                pk1[c >> 1] |= h16(gy);                                       \
            }                                                                 \
        }                                                                     \
    }
    // GS=132: even rows (q0) are 528*lane bytes -> 16B aligned (uint4 ok);
    // odd rows (q0+1) are 8B aligned -> uint2 stores.
    #define DUMP_G() {                                                        \
        unsigned short* d0 = &bufG[q0 * GS + base];                           \
        unsigned short* d1 = &bufG[(q0 + 1) * GS + base];                     \
        *(uint4*)(d0)      = make_uint4(pk0[0], pk0[1], pk0[2], pk0[3]);      \
        *(uint4*)(d0 + 8)  = make_uint4(pk0[4], pk0[5], pk0[6], pk0[7]);      \
        *(uint2*)(d1)      = make_uint2(pk1[0], pk1[1]);                      \
        *(uint2*)(d1 + 4)  = make_uint2(pk1[2], pk1[3]);                      \
        *(uint2*)(d1 + 8)  = make_uint2(pk1[4], pk1[5]);                      \
        *(uint2*)(d1 + 12) = make_uint2(pk1[6], pk1[7]);                      \
    }

    FILTER_PHASE(bufP)
    DUMP_G()
    __syncthreads();                     // g0 visible; all bufP(c0) reads done

    // ---------- issue c1 staging loads (drain hides under MFMA c0) ----------
    const bool tguard = (chunk0 == 62);  // only the last chunk pair can run past TT
    float4 va[12];
    #pragma unroll
    for (int i = 0; i < 12; ++i) {
        const int m = mr + i * 16;
        const int t = t01 + 1 + m;
        va[i] = make_float4(0.f, 0.f, 0.f, 0.f);
        if (m < PROWS && (!tguard || t < TT))
            va[i] = *(const float4*)(pb + (size_t)t * NN + sc * 4);
    }

    // ---------- MFMA: wave wv owns pre rows [wv*16, wv*16+16), all 128 q ----------
    const int pr0 = wv * 16;
    f32x4 acc[8];
    #pragma unroll
    for (int qt = 0; qt < 8; ++qt) acc[qt] = (f32x4){0.f, 0.f, 0.f, 0.f};

    // K=128 per chunk: 4 ks steps of 32. B fragment via 2x ds_read_b64 (GS=132).
    #define MFMA_PHASE(T0) {                                                  \
        const float* abase = ab + (size_t)((T0) + (lane >> 4) * 8) * NN + pr0 + (lane & 15); \
        float an[8];                                                          \
        _Pragma("unroll")                                                     \
        for (int j = 0; j < 8; ++j) an[j] = abase[(size_t)j * NN];            \
        _Pragma("unroll")                                                     \
        for (int ks = 0; ks < 4; ++ks) {                                      \
            f16x8 af;                                                         \
            _Pragma("unroll")                                                 \
            for (int j = 0; j < 8; ++j) af[j] = (_Float16)an[j];              \
            if (ks < 3) {                                                     \
                const float* src = abase + (size_t)((ks + 1) * 32) * NN;      \
                _Pragma("unroll")                                             \
                for (int j = 0; j < 8; ++j) an[j] = src[(size_t)j * NN];      \
            }                                                                 \
            const int koff = ks * 32 + (lane >> 4) * 8;                       \
            _Pragma("unroll")                                                 \
            for (int qt = 0; qt < 8; ++qt) {                                  \
                const unsigned short* gp = &bufG[(qt * 16 + (lane & 15)) * GS + koff]; \
                const uint2 lo = *(const uint2*)(gp);                         \
                const uint2 hi = *(const uint2*)(gp + 4);                     \
                const uint4 u  = make_uint4(lo.x, lo.y, hi.x, hi.y);          \
                const f16x8 bf = __builtin_bit_cast(f16x8, u);                \
                acc[qt] = __builtin_amdgcn_mfma_f32_16x16x32_f16(af, bf, acc[qt], 0, 0, 0); \
            }                                                                 \
        }                                                                     \
    }

    MFMA_PHASE(t00)

    // ---------- store c1 post tile into bufP ----------
    #pragma unroll
    for (int i = 0; i < 12; ++i) {
        const int m = mr + i * 16;
        if (m < PROWS)
            *(uint2*)&bufP[m * NN + sc * 4] =
                make_uint2(pack2(va[i].x, va[i].y), pack2(va[i].z, va[i].w));
    }
    __syncthreads();                     // bufP(c1) ready; bufG(M0) reads done

    // ---------- filter c1 + dump g1 ----------
    FILTER_PHASE(bufP)
    DUMP_G()
    __syncthreads();                     // g1 visible; bufP dead -> reuse for ps

    // ---------- ps flush into dead bufP (overlaps MFMA c1) ----------
    {
        float* psb = (float*)bufP;
        psb[wv * NN + q0]     = ps0;
        psb[wv * NN + q0 + 1] = ps1;
    }

    // ---------- MFMA c1 (accumulates onto acc) ----------
    MFMA_PHASE(t01)
    __syncthreads();                     // psb visible

    // ---------- wpost (both chunks, one column per block) ----------
    if (tid < NN) {
        const float* psb = (const float*)bufP;
        float s = 0.f;
        #pragma unroll
        for (int w = 0; w < NWAVE; ++w) s += psb[w * NN + tid];
        if (chunk0 == 0) s += pb[tid];   // windows miss t=0 once per batch
        if constexpr (ATOMIC) atomicAdd(&wpost[tid], s);
        else wpost[(size_t)bi * NN + tid] = s;
    }

    // ---------- write combined partial: u32-packed f16 pairs, coalesced ----------
    if constexpr (!ATOMIC) {
        unsigned int* dst = part + ((size_t)bi * 8 + wv) * 1024 + lane;
        #pragma unroll
        for (int qt = 0; qt < 8; ++qt) {
            dst[qt * 128]      = pack2(acc[qt][0], acc[qt][1]);
            dst[qt * 128 + 64] = pack2(acc[qt][2], acc[qt][3]);
        }
    } else {
        #pragma unroll
        for (int qt = 0; qt < 8; ++qt)
            #pragma unroll
            for (int rg = 0; rg < 4; ++rg) {
                const int prow = pr0 + (lane >> 4) * 4 + rg;
                const int qcol = qt * 16 + (lane & 15);
                atomicAdd(&outat[prow * NN + qcol], acc[qt][rg]);
            }
    }
    #undef FILTER_PHASE
    #undef DUMP_G
    #undef MFMA_PHASE
}

// fused split-K reduce + hfac + epilogue: 128 blocks x 512 thr.
// Each block's 64 slots share one qt => 16 distinct q: hfac computed in-kernel.
__global__ __launch_bounds__(512)
void finalize_ws(const unsigned int* __restrict__ part, const float* __restrict__ wpost,
                 const int* __restrict__ dtp, const float* __restrict__ W,
                 float* __restrict__ out)
{
    __shared__ float2 red[512];
    __shared__ float  hfs[16];
    const int s    = threadIdx.x & 63;        // slot within block's 64
    const int kq   = threadIdx.x >> 6;        // 0..7
    const int slot = blockIdx.x * 64 + s;     // 0..8191
    const int qt   = (slot >> 7) & 7;         // fixed for whole block
    const int qbase = qt * 16;

    // hfac: 32 threads per q, shfl reduce over wpost[0..NBLK)[q]
    {
        const int qi = threadIdx.x >> 5;      // 0..15
        const int pr = threadIdx.x & 31;
        float hsum = 0.f;
        const int q = qbase + qi;
        #pragma unroll 4
        for (int k = pr; k < NBLK; k += 32) hsum += wpost[(size_t)k * NN + q];
        #pragma unroll
        for (int off = 16; off; off >>= 1) hsum += __shfl_down(hsum, off, 32);
        if (pr == 0) {
            const float dtf   = (float)(*dtp);
            const float alpha = dtf * 1e-3f;
            hfs[qi] = -0.001f * (alpha * (hsum * (1.0f / (float)(BB * TT)) - 0.1f));
        }
    }

    float sx = 0.f, sy = 0.f;
    #pragma unroll 8
    for (int k = kq * (NBLK / 8); k < (kq + 1) * (NBLK / 8); ++k) {
        const unsigned int v = part[(size_t)k * SLOTS + slot];
        const f16x2 h = __builtin_bit_cast(f16x2, v);
        sx += (float)h[0];
        sy += (float)h[1];
    }
    red[threadIdx.x] = make_float2(sx, sy);
    __syncthreads();
    if (threadIdx.x < 64) {
        float tx = red[s].x, ty = red[s].y;
        #pragma unroll
        for (int g = 1; g < 8; ++g) {
            const float2 v = red[g * 64 + s];
            tx += v.x; ty += v.y;
        }
        // un-permute slot -> (p, q)
        const int lane = slot & 63;
        const int rp   = (slot >> 6) & 1;
        const int wv   = slot >> 10;
        const int p    = wv * 16 + ((lane >> 4) << 2) + rp * 2;
        const int qi   = lane & 15;
        const int q    = qbase + qi;
        const float scale = (float)((0.005 - 0.00525) / (double)(BB * TT));
        const float hf = hfs[qi];
        out[p * NN + q]       = fmaf(tx, scale, hf * W[p * NN + q]);
        out[(p + 1) * NN + q] = fmaf(ty, scale, hf * W[(p + 1) * NN + q]);
    }
}

// fallback epilogue when S was atomically accumulated in d_out
__global__ void finalize_at(const float* __restrict__ wpost, const int* __restrict__ dtp,
                            const float* __restrict__ W, float* __restrict__ out)
{
    const int i = (blockIdx.x * 256 + threadIdx.x) * 2;
    const int q = i & 127;
    const float scale = (float)((0.005 - 0.00525) / (double)(BB * TT));
    const float dtf   = (float)(*dtp);
    const float alpha = dtf * 1e-3f;
    const float inv   = 1.0f / (float)(BB * TT);
    const float hf0   = -0.001f * (alpha * (wpost[q]     * inv - 0.1f));
    const float hf1   = -0.001f * (alpha * (wpost[q + 1] * inv - 0.1f));
    float2 sv = *(const float2*)(out + i);
    float2 w  = *(const float2*)(W + i);
    float2 o;
    o.x = fmaf(sv.x, scale, hf0 * w.x);
    o.y = fmaf(sv.y, scale, hf1 * w.y);
    *(float2*)(out + i) = o;
}

extern "C" void kernel_launch(void* const* d_in, const int* in_sizes, int n_in,
                              void* d_out, int out_size, void* d_ws, size_t ws_size,
                              hipStream_t stream)
{
    const float* pre  = (const float*)d_in[0];
    const float* post = (const float*)d_in[1];
    const float* W    = (const float*)d_in[2];
    const int*   dtp  = (const int*)d_in[3];
    float* out = (float*)d_out;

    const size_t part_bytes  = (size_t)NBLK * SLOTS * sizeof(unsigned int); // 16 MiB
    const size_t wpost_bytes = (size_t)NBLK * NN * sizeof(float);           // 256 KiB
    const size_t need = part_bytes + wpost_bytes;

    if (ws_size >= need) {
        unsigned int* part = (unsigned int*)d_ws;
        float* wpost       = (float*)((char*)d_ws + part_bytes);
        hipLaunchKernelGGL((stdp_main<false>), dim3(NBLK), dim3(512), 0, stream,
                           pre, post, dtp, part, wpost, (float*)nullptr);
        hipLaunchKernelGGL(finalize_ws, dim3(SLOTS / 64), dim3(512), 0, stream,
                           part, wpost, dtp, W, out);
    } else {
        // atomic fallback: needs only 512 B of workspace
        float* wpost = (float*)d_ws;
        hipMemsetAsync(d_out, 0, OUTN * sizeof(float), stream);
        hipMemsetAsync(wpost, 0, NN * sizeof(float), stream);
        hipLaunchKernelGGL((stdp_main<true>), dim3(NBLK), dim3(512), 0, stream,
                           pre, post, dtp, (unsigned int*)nullptr, wpost, out);
        hipLaunchKernelGGL(finalize_at, dim3(OUTN / 512), dim3(256), 0, stream,
                           wpost, dtp, W, out);
    }
}

// Round 5
// 173.401 us; speedup vs baseline: 1.2140x; 1.2140x over previous
//
#include <hip/hip_runtime.h>

#define BB 16
#define TT 8192
#define NN 128                     // N_PRE == N_POST
constexpr int CHUNK = 128;         // time-steps per chunk (halved vs round 0)
constexpr int NCHB  = BB * TT / CHUNK;   // 1024 chunks
constexpr int NBLK  = NCHB / 2;          // 512 blocks, 2 chunks each -> 2 blocks/CU
constexpr int OUTN  = NN * NN;           // 16384
constexpr int GS    = 132;         // bufG row stride in halves (264 B, 8B-aligned)
constexpr int SLOTS = OUTN / 2;    // 8192 packed u32 slots per block-slice
constexpr int PROWS = 186;         // staged post rows per chunk: max m = 112+73 = 185
constexpr int NWAVE = 8;           // 512 threads
constexpr int WIN   = CHUNK / NWAVE;     // 16-step filter window per wave

typedef _Float16 f16x8 __attribute__((ext_vector_type(8)));
typedef _Float16 f16x2 __attribute__((ext_vector_type(2)));
typedef float    f32x4 __attribute__((ext_vector_type(4)));

__device__ __forceinline__ unsigned short h16(float x) {
    _Float16 h = (_Float16)x;
    return __builtin_bit_cast(unsigned short, h);
}
__device__ __forceinline__ unsigned int pack2(float x, float y) {
    return (unsigned int)h16(x) | ((unsigned int)h16(y) << 16);
}
__device__ __forceinline__ float2 ldL(const unsigned short* p_lds, int m, int q0) {
    const unsigned int v = *(const unsigned int*)&p_lds[m * NN + q0];
    const f16x2 h = __builtin_bit_cast(f16x2, v);
    return make_float2((float)h[0], (float)h[1]);
}

// grid 512 x 512 threads, 81,408 B LDS -> 2 blocks/CU resident, 16 waves/CU.
// ROUND-5: one-token fix of round 4. Empirical launch_bounds mapping on this
// toolchain: (512,2)->128 VGPR, (512,4)->64, (1024,*)->64 — the 2nd arg acts
// as BLOCKS-per-CU (CUDA semantics), so (512,4) meant 8 waves/SIMD -> 64-reg
// cap -> ~120 MB scratch spill (WRITE_SIZE 136 MB). With (512,2) the cap is
// 256, actual use ~100-128 -> no spill, and REAL residency is still 2
// blocks/CU: 128 VGPR x 8 waves x 2 = 4 waves/SIMD (full), LDS 2x81,408 =
// 162,816 <= 163,840. Co-resident blocks share no barriers -> each fills the
// other's stalls.
// Pipeline per block (chunks c0=2bi, c1=2bi+1, same batch):
// stage c0 -> BAR -> filter c0 -> BAR -> [issue c1 loads | MFMA c0 | store c1]
// -> BAR -> filter c1 -> BAR -> [ps flush | MFMA c1] -> BAR -> wpost + partial.
template<bool ATOMIC>
__global__ __launch_bounds__(512, 2)
void stdp_main(const float* __restrict__ pre, const float* __restrict__ post,
               const int* __restrict__ dtp,
               unsigned int* __restrict__ part, float* __restrict__ wpost,
               float* __restrict__ outat)
{
    __shared__ __align__(16) unsigned short bufP[PROWS * NN];   // 47,616 B post tile
    __shared__ __align__(16) unsigned short bufG[NN * GS];      // 33,792 B g tile

    const int tid    = threadIdx.x;
    const int bi     = blockIdx.x;
    const int c0g    = bi * 2;           // global chunk ids c0g, c0g+1 (same batch)
    const int b      = c0g >> 6;         // 64 chunks of 128 per batch
    const int chunk0 = c0g & 63;         // even, 0..62
    const int t00    = chunk0 * CHUNK;
    const int t01    = t00 + CHUNK;
    const int wv     = tid >> 6;         // wave 0..7
    const int lane   = tid & 63;

    const float dtf = (float)(*dtp);
    const float r   = expf(-dtf * (1.0f / 20.0f));

    const float* pb = post + (size_t)b * TT * NN;
    const float* ab = pre  + (size_t)b * TT * NN;

    const int sc = tid & 31;             // staging: float4 column
    const int mr = tid >> 5;             // staging: starting row (0..15)

    // ---------- stage c0 post tile into bufP ----------
    // chunk0 <= 62 -> max t = 62*128 + 186 = 8122 < TT, no guard needed
    for (int m = mr; m < PROWS; m += 16) {
        const int t = t00 + 1 + m;
        const float4 v = *(const float4*)(pb + (size_t)t * NN + sc * 4);
        *(uint2*)&bufP[m * NN + sc * 4] = make_uint2(pack2(v.x, v.y), pack2(v.z, v.w));
    }
    __syncthreads();

    const int q0   = lane * 2;
    const int base = wv * WIN;           // window start (16 steps per wave)

    // ---------- filter: window WIN steps, 2 q per lane ----------
    unsigned int pk0[8], pk1[8];
    float ps0 = 0.f, ps1 = 0.f;          // accumulated across BOTH chunks
    // Startup g[15] = sum_{tau=1..59} r^tau * P[base+14+tau], 4 strided ILP
    // chains (dep depth 15). Then backward recurrence c=14..0:
    // g[c] = r*(g[c+1] + P[base+c]) - r^60 * P[base+c+59].
    #define FILTER_PHASE(SRC) {                                               \
        const float r2 = r * r, r3 = r2 * r, r4 = r2 * r2;                    \
        float2 p = ldL(SRC, base + 15, q0);      /* tau=1 */                  \
        ps0 += p.x; ps1 += p.y;                                               \
        float gx0 = r  * p.x, gy0 = r  * p.y;                                 \
        p = ldL(SRC, base + 16, q0);             /* tau=2 */                  \
        float gx1 = r2 * p.x, gy1 = r2 * p.y;                                 \
        p = ldL(SRC, base + 17, q0);             /* tau=3 */                  \
        float gx2 = r3 * p.x, gy2 = r3 * p.y;                                 \
        p = ldL(SRC, base + 18, q0);             /* tau=4 */                  \
        float gx3 = r4 * p.x, gy3 = r4 * p.y;                                 \
        float wA = r * r4, wB = r2 * r4, wC = r3 * r4, wD = r4 * r4;          \
        _Pragma("unroll")                                                     \
        for (int j = 1; j < 15; ++j) {                                        \
            p = ldL(SRC, base + 15 + 4 * j, q0);                              \
            gx0 = fmaf(wA, p.x, gx0); gy0 = fmaf(wA, p.y, gy0);               \
            p = ldL(SRC, base + 16 + 4 * j, q0);                              \
            gx1 = fmaf(wB, p.x, gx1); gy1 = fmaf(wB, p.y, gy1);               \
            p = ldL(SRC, base + 17 + 4 * j, q0);                              \
            gx2 = fmaf(wC, p.x, gx2); gy2 = fmaf(wC, p.y, gy2);               \
            if (j < 14) {                                                     \
                p = ldL(SRC, base + 18 + 4 * j, q0);                          \
                gx3 = fmaf(wD, p.x, gx3); gy3 = fmaf(wD, p.y, gy3);           \
            }                                                                 \
            wA *= r4; wB *= r4; wC *= r4; wD *= r4;                           \
        }                                                                     \
        const float r8 = r4 * r4, r16 = r8 * r8, r32 = r16 * r16;             \
        const float r60 = ((r32 * r16) * r8) * r4;                            \
        float gx = (gx0 + gx1) + (gx2 + gx3);                                 \
        float gy = (gy0 + gy1) + (gy2 + gy3);                                 \
        pk0[7] = (unsigned int)h16(gx) << 16;                                 \
        pk1[7] = (unsigned int)h16(gy) << 16;                                 \
        _Pragma("unroll")                                                     \
        for (int c = 14; c >= 0; --c) {                                       \
            const float2 p1  = ldL(SRC, base + c,      q0);                   \
            const float2 p60 = ldL(SRC, base + c + 59, q0);                   \
            gx = r * (gx + p1.x) - r60 * p60.x;                               \
            gy = r * (gy + p1.y) - r60 * p60.y;                               \
            ps0 += p1.x; ps1 += p1.y;                                         \
            if (c & 1) {                                                      \
                pk0[c >> 1] = (unsigned int)h16(gx) << 16;                    \
                pk1[c >> 1] = (unsigned int)h16(gy) << 16;                    \
            } else {                                                          \
                pk0[c >> 1] |= h16(gx);                                       \
                pk1[c >> 1] |= h16(gy);                                       \
            }                                                                 \
        }                                                                     \
    }
    // GS=132: even rows (q0) are 528*lane bytes -> 16B aligned (uint4 ok);
    // odd rows (q0+1) are 8B aligned -> uint2 stores.
    // Side benefit vs GS=264: bank conflicts dropped 1.47M -> 131K.
    #define DUMP_G() {                                                        \
        unsigned short* d0 = &bufG[q0 * GS + base];                           \
        unsigned short* d1 = &bufG[(q0 + 1) * GS + base];                     \
        *(uint4*)(d0)      = make_uint4(pk0[0], pk0[1], pk0[2], pk0[3]);      \
        *(uint4*)(d0 + 8)  = make_uint4(pk0[4], pk0[5], pk0[6], pk0[7]);      \
        *(uint2*)(d1)      = make_uint2(pk1[0], pk1[1]);                      \
        *(uint2*)(d1 + 4)  = make_uint2(pk1[2], pk1[3]);                      \
        *(uint2*)(d1 + 8)  = make_uint2(pk1[4], pk1[5]);                      \
        *(uint2*)(d1 + 12) = make_uint2(pk1[6], pk1[7]);                      \
    }

    FILTER_PHASE(bufP)
    DUMP_G()
    __syncthreads();                     // g0 visible; all bufP(c0) reads done

    // ---------- issue c1 staging loads (drain hides under MFMA c0) ----------
    const bool tguard = (chunk0 == 62);  // only the last chunk pair can run past TT
    float4 va[12];
    #pragma unroll
    for (int i = 0; i < 12; ++i) {
        const int m = mr + i * 16;
        const int t = t01 + 1 + m;
        va[i] = make_float4(0.f, 0.f, 0.f, 0.f);
        if (m < PROWS && (!tguard || t < TT))
            va[i] = *(const float4*)(pb + (size_t)t * NN + sc * 4);
    }

    // ---------- MFMA: wave wv owns pre rows [wv*16, wv*16+16), all 128 q ----------
    const int pr0 = wv * 16;
    f32x4 acc[8];
    #pragma unroll
    for (int qt = 0; qt < 8; ++qt) acc[qt] = (f32x4){0.f, 0.f, 0.f, 0.f};

    // K=128 per chunk: 4 ks steps of 32. B fragment via 2x ds_read_b64 (GS=132).
    #define MFMA_PHASE(T0) {                                                  \
        const float* abase = ab + (size_t)((T0) + (lane >> 4) * 8) * NN + pr0 + (lane & 15); \
        float an[8];                                                          \
        _Pragma("unroll")                                                     \
        for (int j = 0; j < 8; ++j) an[j] = abase[(size_t)j * NN];            \
        _Pragma("unroll")                                                     \
        for (int ks = 0; ks < 4; ++ks) {                                      \
            f16x8 af;                                                         \
            _Pragma("unroll")                                                 \
            for (int j = 0; j < 8; ++j) af[j] = (_Float16)an[j];              \
            if (ks < 3) {                                                     \
                const float* src = abase + (size_t)((ks + 1) * 32) * NN;      \
                _Pragma("unroll")                                             \
                for (int j = 0; j < 8; ++j) an[j] = src[(size_t)j * NN];      \
            }                                                                 \
            const int koff = ks * 32 + (lane >> 4) * 8;                       \
            _Pragma("unroll")                                                 \
            for (int qt = 0; qt < 8; ++qt) {                                  \
                const unsigned short* gp = &bufG[(qt * 16 + (lane & 15)) * GS + koff]; \
                const uint2 lo = *(const uint2*)(gp);                         \
                const uint2 hi = *(const uint2*)(gp + 4);                     \
                const uint4 u  = make_uint4(lo.x, lo.y, hi.x, hi.y);          \
                const f16x8 bf = __builtin_bit_cast(f16x8, u);                \
                acc[qt] = __builtin_amdgcn_mfma_f32_16x16x32_f16(af, bf, acc[qt], 0, 0, 0); \
            }                                                                 \
        }                                                                     \
    }

    MFMA_PHASE(t00)

    // ---------- store c1 post tile into bufP ----------
    #pragma unroll
    for (int i = 0; i < 12; ++i) {
        const int m = mr + i * 16;
        if (m < PROWS)
            *(uint2*)&bufP[m * NN + sc * 4] =
                make_uint2(pack2(va[i].x, va[i].y), pack2(va[i].z, va[i].w));
    }
    __syncthreads();                     // bufP(c1) ready; bufG(M0) reads done

    // ---------- filter c1 + dump g1 ----------
    FILTER_PHASE(bufP)
    DUMP_G()
    __syncthreads();                     // g1 visible; bufP dead -> reuse for ps

    // ---------- ps flush into dead bufP (overlaps MFMA c1) ----------
    {
        float* psb = (float*)bufP;
        psb[wv * NN + q0]     = ps0;
        psb[wv * NN + q0 + 1] = ps1;
    }

    // ---------- MFMA c1 (accumulates onto acc) ----------
    MFMA_PHASE(t01)
    __syncthreads();                     // psb visible

    // ---------- wpost (both chunks, one column per block) ----------
    if (tid < NN) {
        const float* psb = (const float*)bufP;
        float s = 0.f;
        #pragma unroll
        for (int w = 0; w < NWAVE; ++w) s += psb[w * NN + tid];
        if (chunk0 == 0) s += pb[tid];   // windows miss t=0 once per batch
        if constexpr (ATOMIC) atomicAdd(&wpost[tid], s);
        else wpost[(size_t)bi * NN + tid] = s;
    }

    // ---------- write combined partial: u32-packed f16 pairs, coalesced ----------
    if constexpr (!ATOMIC) {
        unsigned int* dst = part + ((size_t)bi * 8 + wv) * 1024 + lane;
        #pragma unroll
        for (int qt = 0; qt < 8; ++qt) {
            dst[qt * 128]      = pack2(acc[qt][0], acc[qt][1]);
            dst[qt * 128 + 64] = pack2(acc[qt][2], acc[qt][3]);
        }
    } else {
        #pragma unroll
        for (int qt = 0; qt < 8; ++qt)
            #pragma unroll
            for (int rg = 0; rg < 4; ++rg) {
                const int prow = pr0 + (lane >> 4) * 4 + rg;
                const int qcol = qt * 16 + (lane & 15);
                atomicAdd(&outat[prow * NN + qcol], acc[qt][rg]);
            }
    }
    #undef FILTER_PHASE
    #undef DUMP_G
    #undef MFMA_PHASE
}

// fused split-K reduce + hfac + epilogue: 128 blocks x 512 thr.
// Each block's 64 slots share one qt => 16 distinct q: hfac computed in-kernel.
__global__ __launch_bounds__(512)
void finalize_ws(const unsigned int* __restrict__ part, const float* __restrict__ wpost,
                 const int* __restrict__ dtp, const float* __restrict__ W,
                 float* __restrict__ out)
{
    __shared__ float2 red[512];
    __shared__ float  hfs[16];
    const int s    = threadIdx.x & 63;        // slot within block's 64
    const int kq   = threadIdx.x >> 6;        // 0..7
    const int slot = blockIdx.x * 64 + s;     // 0..8191
    const int qt   = (slot >> 7) & 7;         // fixed for whole block
    const int qbase = qt * 16;

    // hfac: 32 threads per q, shfl reduce over wpost[0..NBLK)[q]
    {
        const int qi = threadIdx.x >> 5;      // 0..15
        const int pr = threadIdx.x & 31;
        float hsum = 0.f;
        const int q = qbase + qi;
        #pragma unroll 4
        for (int k = pr; k < NBLK; k += 32) hsum += wpost[(size_t)k * NN + q];
        #pragma unroll
        for (int off = 16; off; off >>= 1) hsum += __shfl_down(hsum, off, 32);
        if (pr == 0) {
            const float dtf   = (float)(*dtp);
            const float alpha = dtf * 1e-3f;
            hfs[qi] = -0.001f * (alpha * (hsum * (1.0f / (float)(BB * TT)) - 0.1f));
        }
    }

    float sx = 0.f, sy = 0.f;
    #pragma unroll 8
    for (int k = kq * (NBLK / 8); k < (kq + 1) * (NBLK / 8); ++k) {
        const unsigned int v = part[(size_t)k * SLOTS + slot];
        const f16x2 h = __builtin_bit_cast(f16x2, v);
        sx += (float)h[0];
        sy += (float)h[1];
    }
    red[threadIdx.x] = make_float2(sx, sy);
    __syncthreads();
    if (threadIdx.x < 64) {
        float tx = red[s].x, ty = red[s].y;
        #pragma unroll
        for (int g = 1; g < 8; ++g) {
            const float2 v = red[g * 64 + s];
            tx += v.x; ty += v.y;
        }
        // un-permute slot -> (p, q)
        const int lane = slot & 63;
        const int rp   = (slot >> 6) & 1;
        const int wv   = slot >> 10;
        const int p    = wv * 16 + ((lane >> 4) << 2) + rp * 2;
        const int qi   = lane & 15;
        const int q    = qbase + qi;
        const float scale = (float)((0.005 - 0.00525) / (double)(BB * TT));
        const float hf = hfs[qi];
        out[p * NN + q]       = fmaf(tx, scale, hf * W[p * NN + q]);
        out[(p + 1) * NN + q] = fmaf(ty, scale, hf * W[(p + 1) * NN + q]);
    }
}

// fallback epilogue when S was atomically accumulated in d_out
__global__ void finalize_at(const float* __restrict__ wpost, const int* __restrict__ dtp,
                            const float* __restrict__ W, float* __restrict__ out)
{
    const int i = (blockIdx.x * 256 + threadIdx.x) * 2;
    const int q = i & 127;
    const float scale = (float)((0.005 - 0.00525) / (double)(BB * TT));
    const float dtf   = (float)(*dtp);
    const float alpha = dtf * 1e-3f;
    const float inv   = 1.0f / (float)(BB * TT);
    const float hf0   = -0.001f * (alpha * (wpost[q]     * inv - 0.1f));
    const float hf1   = -0.001f * (alpha * (wpost[q + 1] * inv - 0.1f));
    float2 sv = *(const float2*)(out + i);
    float2 w  = *(const float2*)(W + i);
    float2 o;
    o.x = fmaf(sv.x, scale, hf0 * w.x);
    o.y = fmaf(sv.y, scale, hf1 * w.y);
    *(float2*)(out + i) = o;
}

extern "C" void kernel_launch(void* const* d_in, const int* in_sizes, int n_in,
                              void* d_out, int out_size, void* d_ws, size_t ws_size,
                              hipStream_t stream)
{
    const float* pre  = (const float*)d_in[0];
    const float* post = (const float*)d_in[1];
    const float* W    = (const float*)d_in[2];
    const int*   dtp  = (const int*)d_in[3];
    float* out = (float*)d_out;

    const size_t part_bytes  = (size_t)NBLK * SLOTS * sizeof(unsigned int); // 16 MiB
    const size_t wpost_bytes = (size_t)NBLK * NN * sizeof(float);           // 256 KiB
    const size_t need = part_bytes + wpost_bytes;

    if (ws_size >= need) {
        unsigned int* part = (unsigned int*)d_ws;
        float* wpost       = (float*)((char*)d_ws + part_bytes);
        hipLaunchKernelGGL((stdp_main<false>), dim3(NBLK), dim3(512), 0, stream,
                           pre, post, dtp, part, wpost, (float*)nullptr);
        hipLaunchKernelGGL(finalize_ws, dim3(SLOTS / 64), dim3(512), 0, stream,
                           part, wpost, dtp, W, out);
    } else {
        // atomic fallback: needs only 512 B of workspace
        float* wpost = (float*)d_ws;
        hipMemsetAsync(d_out, 0, OUTN * sizeof(float), stream);
        hipMemsetAsync(wpost, 0, NN * sizeof(float), stream);
        hipLaunchKernelGGL((stdp_main<true>), dim3(NBLK), dim3(512), 0, stream,
                           pre, post, dtp, (unsigned int*)nullptr, wpost, out);
        hipLaunchKernelGGL(finalize_at, dim3(OUTN / 512), dim3(256), 0, stream,
                           wpost, dtp, W, out);
    }
}

// Round 6
// 173.327 us; speedup vs baseline: 1.2145x; 1.0004x over previous
//
#include <hip/hip_runtime.h>

#define BB 16
#define TT 8192
#define NN 128                     // N_PRE == N_POST
constexpr int CHUNK = 256;         // time-steps per block (1 chunk per block)
constexpr int NBLK  = BB * TT / CHUNK;   // 512 blocks -> 2 blocks/CU
constexpr int OUTN  = NN * NN;           // 16384
constexpr int GS    = 260;         // bufG row stride in halves (520 B, 8B-aligned)
constexpr int SLOTS = OUTN / 2;    // 8192 packed u32 slots per block-slice
constexpr int NWAVE = 8;           // 512 threads
constexpr int WIN   = CHUNK / NWAVE;     // 32-step filter window per wave

typedef _Float16 f16x8 __attribute__((ext_vector_type(8)));
typedef _Float16 f16x2 __attribute__((ext_vector_type(2)));
typedef float    f32x4 __attribute__((ext_vector_type(4)));

__device__ __forceinline__ unsigned short h16(float x) {
    _Float16 h = (_Float16)x;
    return __builtin_bit_cast(unsigned short, h);
}
__device__ __forceinline__ unsigned int pack2(float x, float y) {
    return (unsigned int)h16(x) | ((unsigned int)h16(y) << 16);
}

// grid 512 x 512 threads, 70,656 B LDS -> 2 blocks/CU with real margin.
// ROUND-6: drop bufP staging entirely. R5 evidence: (a) 162,816/163,840 B
// does NOT co-schedule 2 blocks (occupancy 19% = 1/CU); (b) per-block time
// scales with work -> the win is removing work+barriers, not hiding them.
// Filter reads post directly from global (full 512B-coalesced rows, float2
// per lane, L2/L3-resident; ~2.8x row re-read across overlapping windows).
// This deletes the staging loops, two f16 conversion passes, 47.6 KB of LDS,
// and 4 of 5 barriers. One 256-step chunk per block, WIN=32 per wave,
// K=256 MFMA, same part/finalize layout as round 5.
template<bool ATOMIC>
__global__ __launch_bounds__(512, 2)
void stdp_main(const float* __restrict__ pre, const float* __restrict__ post,
               const int* __restrict__ dtp,
               unsigned int* __restrict__ part, float* __restrict__ wpost,
               float* __restrict__ outat)
{
    __shared__ __align__(16) unsigned short bufG[NN * GS];  // 66,560 B g tile
    __shared__ float lds_ps[NWAVE * NN];                    // 4 KB

    const int tid  = threadIdx.x;
    const int bi   = blockIdx.x;
    const int b    = bi >> 5;            // batch (32 chunks of 256 per batch)
    const int ch   = bi & 31;            // chunk index in batch
    const int t00  = ch * CHUNK;
    const int wv   = tid >> 6;           // wave 0..7
    const int lane = tid & 63;

    const float dtf = (float)(*dtp);
    const float r   = expf(-dtf * (1.0f / 20.0f));

    const float* pb = post + (size_t)b * TT * NN;
    const float* ab = pre  + (size_t)b * TT * NN;

    const int q0   = lane * 2;
    const int base = wv * WIN;           // window start (32 steps per wave)
    // P(m) = post[t00 + 1 + m][q0..q0+1]; valid iff m <= mlim
    const float* prow = pb + (size_t)(t00 + 1) * NN + q0;
    const int mlim = TT - 2 - t00;

    // ---------- filter: window WIN=32, 2 q per lane, direct global reads ----------
    unsigned int pk0[16], pk1[16];
    float ps0 = 0.f, ps1 = 0.f;
    // Startup g[31] = sum_{tau=1..59} r^tau * P(base+30+tau), 4 strided ILP
    // chains (dep depth 15). Then backward recurrence c=30..0:
    // g[c] = r*(g[c+1] + P(base+c)) - r^60 * P(base+c+59).
    #define LDF(m) (*(const float2*)(prow + (size_t)(m) * NN))
    #define LDG(m) (((m) <= mlim) ? LDF(m) : make_float2(0.f, 0.f))
    #define FILTER_BODY(LD) {                                                 \
        const float r2 = r * r, r3 = r2 * r, r4 = r2 * r2;                    \
        float2 p = LD(base + 31);                /* tau=1 */                  \
        ps0 += p.x; ps1 += p.y;                                               \
        float gx0 = r  * p.x, gy0 = r  * p.y;                                 \
        p = LD(base + 32);                       /* tau=2 */                  \
        float gx1 = r2 * p.x, gy1 = r2 * p.y;                                 \
        p = LD(base + 33);                       /* tau=3 */                  \
        float gx2 = r3 * p.x, gy2 = r3 * p.y;                                 \
        p = LD(base + 34);                       /* tau=4 */                  \
        float gx3 = r4 * p.x, gy3 = r4 * p.y;                                 \
        float wA = r * r4, wB = r2 * r4, wC = r3 * r4, wD = r4 * r4;          \
        _Pragma("unroll")                                                     \
        for (int j = 1; j < 15; ++j) {                                        \
            p = LD(base + 31 + 4 * j);                                        \
            gx0 = fmaf(wA, p.x, gx0); gy0 = fmaf(wA, p.y, gy0);               \
            p = LD(base + 32 + 4 * j);                                        \
            gx1 = fmaf(wB, p.x, gx1); gy1 = fmaf(wB, p.y, gy1);               \
            p = LD(base + 33 + 4 * j);                                        \
            gx2 = fmaf(wC, p.x, gx2); gy2 = fmaf(wC, p.y, gy2);               \
            if (j < 14) {                                                     \
                p = LD(base + 34 + 4 * j);                                    \
                gx3 = fmaf(wD, p.x, gx3); gy3 = fmaf(wD, p.y, gy3);           \
            }                                                                 \
            wA *= r4; wB *= r4; wC *= r4; wD *= r4;                           \
        }                                                                     \
        const float r8 = r4 * r4, r16 = r8 * r8, r32 = r16 * r16;             \
        const float r60 = ((r32 * r16) * r8) * r4;                            \
        float gx = (gx0 + gx1) + (gx2 + gx3);                                 \
        float gy = (gy0 + gy1) + (gy2 + gy3);                                 \
        pk0[15] = (unsigned int)h16(gx) << 16;                                \
        pk1[15] = (unsigned int)h16(gy) << 16;                                \
        _Pragma("unroll")                                                     \
        for (int c = 30; c >= 0; --c) {                                       \
            const float2 p1  = LD(base + c);                                  \
            const float2 p60 = LD(base + c + 59);                             \
            gx = r * (gx + p1.x) - r60 * p60.x;                               \
            gy = r * (gy + p1.y) - r60 * p60.y;                               \
            ps0 += p1.x; ps1 += p1.y;                                         \
            if (c & 1) {                                                      \
                pk0[c >> 1] = (unsigned int)h16(gx) << 16;                    \
                pk1[c >> 1] = (unsigned int)h16(gy) << 16;                    \
            } else {                                                          \
                pk0[c >> 1] |= h16(gx);                                       \
                pk1[c >> 1] |= h16(gy);                                       \
            }                                                                 \
        }                                                                     \
    }

    if (base + 89 <= mlim) {             // fast path: whole window in-range
        FILTER_BODY(LDF)
    } else {                             // only tail waves of ch==31
        FILTER_BODY(LDG)
    }

    // ---------- dump g + ps ----------
    // GS=260: even rows 16B-aligned (uint4), odd rows 8B-aligned (uint2).
    {
        unsigned short* d0 = &bufG[q0 * GS + base];
        unsigned short* d1 = &bufG[(q0 + 1) * GS + base];
        *(uint4*)(d0)      = make_uint4(pk0[0],  pk0[1],  pk0[2],  pk0[3]);
        *(uint4*)(d0 + 8)  = make_uint4(pk0[4],  pk0[5],  pk0[6],  pk0[7]);
        *(uint4*)(d0 + 16) = make_uint4(pk0[8],  pk0[9],  pk0[10], pk0[11]);
        *(uint4*)(d0 + 24) = make_uint4(pk0[12], pk0[13], pk0[14], pk0[15]);
        *(uint2*)(d1)      = make_uint2(pk1[0],  pk1[1]);
        *(uint2*)(d1 + 4)  = make_uint2(pk1[2],  pk1[3]);
        *(uint2*)(d1 + 8)  = make_uint2(pk1[4],  pk1[5]);
        *(uint2*)(d1 + 12) = make_uint2(pk1[6],  pk1[7]);
        *(uint2*)(d1 + 16) = make_uint2(pk1[8],  pk1[9]);
        *(uint2*)(d1 + 20) = make_uint2(pk1[10], pk1[11]);
        *(uint2*)(d1 + 24) = make_uint2(pk1[12], pk1[13]);
        *(uint2*)(d1 + 28) = make_uint2(pk1[14], pk1[15]);
        lds_ps[wv * NN + q0]     = ps0;
        lds_ps[wv * NN + q0 + 1] = ps1;
    }
    __syncthreads();                     // the ONLY barrier: g + ps visible

    // ---------- wpost (store overlaps MFMA below) ----------
    if (tid < NN) {
        float s = 0.f;
        #pragma unroll
        for (int w = 0; w < NWAVE; ++w) s += lds_ps[w * NN + tid];
        if (ch == 0) s += pb[tid];       // window (t0, t0+256] misses t=0 once per batch
        if constexpr (ATOMIC) atomicAdd(&wpost[tid], s);
        else wpost[(size_t)bi * NN + tid] = s;
    }

    // ---------- MFMA: wave wv owns pre rows [wv*16, wv*16+16), all 128 q ----------
    const int pr0 = wv * 16;
    f32x4 acc[8];
    #pragma unroll
    for (int qt = 0; qt < 8; ++qt) acc[qt] = (f32x4){0.f, 0.f, 0.f, 0.f};

    {
        const float* abase = ab + (size_t)(t00 + (lane >> 4) * 8) * NN + pr0 + (lane & 15);
        float an[8];
        #pragma unroll
        for (int j = 0; j < 8; ++j) an[j] = abase[(size_t)j * NN];
        #pragma unroll
        for (int ks = 0; ks < 8; ++ks) {
            f16x8 af;
            #pragma unroll
            for (int j = 0; j < 8; ++j) af[j] = (_Float16)an[j];
            if (ks < 7) {
                const float* src = abase + (size_t)((ks + 1) * 32) * NN;
                #pragma unroll
                for (int j = 0; j < 8; ++j) an[j] = src[(size_t)j * NN];
            }
            const int koff = ks * 32 + (lane >> 4) * 8;
            #pragma unroll
            for (int qt = 0; qt < 8; ++qt) {
                const unsigned short* gp = &bufG[(qt * 16 + (lane & 15)) * GS + koff];
                const uint2 lo = *(const uint2*)(gp);
                const uint2 hi = *(const uint2*)(gp + 4);
                const uint4 u  = make_uint4(lo.x, lo.y, hi.x, hi.y);
                const f16x8 bf = __builtin_bit_cast(f16x8, u);
                acc[qt] = __builtin_amdgcn_mfma_f32_16x16x32_f16(af, bf, acc[qt], 0, 0, 0);
            }
        }
    }

    // ---------- write partial: u32-packed f16 pairs, coalesced ----------
    if constexpr (!ATOMIC) {
        unsigned int* dst = part + ((size_t)bi * 8 + wv) * 1024 + lane;
        #pragma unroll
        for (int qt = 0; qt < 8; ++qt) {
            dst[qt * 128]      = pack2(acc[qt][0], acc[qt][1]);
            dst[qt * 128 + 64] = pack2(acc[qt][2], acc[qt][3]);
        }
    } else {
        #pragma unroll
        for (int qt = 0; qt < 8; ++qt)
            #pragma unroll
            for (int rg = 0; rg < 4; ++rg) {
                const int prow_o = pr0 + (lane >> 4) * 4 + rg;
                const int qcol   = qt * 16 + (lane & 15);
                atomicAdd(&outat[prow_o * NN + qcol], acc[qt][rg]);
            }
    }
    #undef FILTER_BODY
    #undef LDF
    #undef LDG
}

// fused split-K reduce + hfac + epilogue: 128 blocks x 512 thr.
// Each block's 64 slots share one qt => 16 distinct q: hfac computed in-kernel.
__global__ __launch_bounds__(512)
void finalize_ws(const unsigned int* __restrict__ part, const float* __restrict__ wpost,
                 const int* __restrict__ dtp, const float* __restrict__ W,
                 float* __restrict__ out)
{
    __shared__ float2 red[512];
    __shared__ float  hfs[16];
    const int s    = threadIdx.x & 63;        // slot within block's 64
    const int kq   = threadIdx.x >> 6;        // 0..7
    const int slot = blockIdx.x * 64 + s;     // 0..8191
    const int qt   = (slot >> 7) & 7;         // fixed for whole block
    const int qbase = qt * 16;

    // hfac: 32 threads per q, shfl reduce over wpost[0..NBLK)[q]
    {
        const int qi = threadIdx.x >> 5;      // 0..15
        const int pr = threadIdx.x & 31;
        float hsum = 0.f;
        const int q = qbase + qi;
        #pragma unroll 4
        for (int k = pr; k < NBLK; k += 32) hsum += wpost[(size_t)k * NN + q];
        #pragma unroll
        for (int off = 16; off; off >>= 1) hsum += __shfl_down(hsum, off, 32);
        if (pr == 0) {
            const float dtf   = (float)(*dtp);
            const float alpha = dtf * 1e-3f;
            hfs[qi] = -0.001f * (alpha * (hsum * (1.0f / (float)(BB * TT)) - 0.1f));
        }
    }

    float sx = 0.f, sy = 0.f;
    #pragma unroll 8
    for (int k = kq * (NBLK / 8); k < (kq + 1) * (NBLK / 8); ++k) {
        const unsigned int v = part[(size_t)k * SLOTS + slot];
        const f16x2 h = __builtin_bit_cast(f16x2, v);
        sx += (float)h[0];
        sy += (float)h[1];
    }
    red[threadIdx.x] = make_float2(sx, sy);
    __syncthreads();
    if (threadIdx.x < 64) {
        float tx = red[s].x, ty = red[s].y;
        #pragma unroll
        for (int g = 1; g < 8; ++g) {
            const float2 v = red[g * 64 + s];
            tx += v.x; ty += v.y;
        }
        // un-permute slot -> (p, q)
        const int lane = slot & 63;
        const int rp   = (slot >> 6) & 1;
        const int wv   = slot >> 10;
        const int p    = wv * 16 + ((lane >> 4) << 2) + rp * 2;
        const int qi   = lane & 15;
        const int q    = qbase + qi;
        const float scale = (float)((0.005 - 0.00525) / (double)(BB * TT));
        const float hf = hfs[qi];
        out[p * NN + q]       = fmaf(tx, scale, hf * W[p * NN + q]);
        out[(p + 1) * NN + q] = fmaf(ty, scale, hf * W[(p + 1) * NN + q]);
    }
}

// fallback epilogue when S was atomically accumulated in d_out
__global__ void finalize_at(const float* __restrict__ wpost, const int* __restrict__ dtp,
                            const float* __restrict__ W, float* __restrict__ out)
{
    const int i = (blockIdx.x * 256 + threadIdx.x) * 2;
    const int q = i & 127;
    const float scale = (float)((0.005 - 0.00525) / (double)(BB * TT));
    const float dtf   = (float)(*dtp);
    const float alpha = dtf * 1e-3f;
    const float inv   = 1.0f / (float)(BB * TT);
    const float hf0   = -0.001f * (alpha * (wpost[q]     * inv - 0.1f));
    const float hf1   = -0.001f * (alpha * (wpost[q + 1] * inv - 0.1f));
    float2 sv = *(const float2*)(out + i);
    float2 w  = *(const float2*)(W + i);
    float2 o;
    o.x = fmaf(sv.x, scale, hf0 * w.x);
    o.y = fmaf(sv.y, scale, hf1 * w.y);
    *(float2*)(out + i) = o;
}

extern "C" void kernel_launch(void* const* d_in, const int* in_sizes, int n_in,
                              void* d_out, int out_size, void* d_ws, size_t ws_size,
                              hipStream_t stream)
{
    const float* pre  = (const float*)d_in[0];
    const float* post = (const float*)d_in[1];
    const float* W    = (const float*)d_in[2];
    const int*   dtp  = (const int*)d_in[3];
    float* out = (float*)d_out;

    const size_t part_bytes  = (size_t)NBLK * SLOTS * sizeof(unsigned int); // 16 MiB
    const size_t wpost_bytes = (size_t)NBLK * NN * sizeof(float);           // 256 KiB
    const size_t need = part_bytes + wpost_bytes;

    if (ws_size >= need) {
        unsigned int* part = (unsigned int*)d_ws;
        float* wpost       = (float*)((char*)d_ws + part_bytes);
        hipLaunchKernelGGL((stdp_main<false>), dim3(NBLK), dim3(512), 0, stream,
                           pre, post, dtp, part, wpost, (float*)nullptr);
        hipLaunchKernelGGL(finalize_ws, dim3(SLOTS / 64), dim3(512), 0, stream,
                           part, wpost, dtp, W, out);
    } else {
        // atomic fallback: needs only 512 B of workspace
        float* wpost = (float*)d_ws;
        hipMemsetAsync(d_out, 0, OUTN * sizeof(float), stream);
        hipMemsetAsync(wpost, 0, NN * sizeof(float), stream);
        hipLaunchKernelGGL((stdp_main<true>), dim3(NBLK), dim3(512), 0, stream,
                           pre, post, dtp, (unsigned int*)nullptr, wpost, out);
        hipLaunchKernelGGL(finalize_at, dim3(OUTN / 512), dim3(256), 0, stream,
                           wpost, dtp, W, out);
    }
}